// Round 11
// baseline (452.052 us; speedup 1.0000x reference)
//
#include <hip/hip_runtime.h>

#define NN 50000
#define EE 500000
#define FD 128
#define HD 64
#define NET 3
#define CSTRIDE 650000   // E + 3N (x4 padding: <=3 pads per node)

__device__ __forceinline__ unsigned short f2bf(float f) {
    union { float f; unsigned int i; } c; c.f = f;
    unsigned int u = c.i;
    return (unsigned short)((u + 0x7fffu + ((u >> 16) & 1u)) >> 16);   // RNE
}
__device__ __forceinline__ float tanh_fast(float x) {
    float e = __expf(2.0f * x);
    return 1.0f - __fdividef(2.0f, e + 1.0f);
}
// lo bf16 of a packed u32 -> f32 (exact)
__device__ __forceinline__ float bflo(unsigned int u) { return __uint_as_float(u << 16); }
// hi bf16 -> f32 APPROX (low mantissa garbage <= 2^-8 rel; below bf16 noise)
__device__ __forceinline__ float bfhiA(unsigned int u) { return __uint_as_float(u); }
// exact hi
__device__ __forceinline__ float bfhiX(unsigned int u) { return __uint_as_float(u & 0xffff0000u); }

// ---------------- prep + count + W0 transpose (merged ranges) ----------------
#define PREP_T (NN * FD / 4 + 48 + FD * HD)
__global__ void k_prepcount(const float* __restrict__ feat, unsigned short* __restrict__ featb,
                            unsigned short* __restrict__ h1b, const float* __restrict__ W0,
                            float* __restrict__ w0t,
                            const int* __restrict__ d0, const int* __restrict__ d1,
                            const int* __restrict__ d2, int* __restrict__ cnt) {
    int t = blockIdx.x * 256 + threadIdx.x;
    if (t < NN * FD / 4) {                       // feat cvt, one float4 per thread
        float4 v = *(const float4*)(feat + (size_t)t * 4);
        ushort4 o;
        o.x = f2bf(v.x); o.y = f2bf(v.y); o.z = f2bf(v.z); o.w = f2bf(v.w);
        *(ushort4*)(featb + (size_t)t * 4) = o;
    } else if (t < NN * FD / 4 + 32) {           // zero row NN of featb
        int i = t - NN * FD / 4;
        *(ushort4*)(featb + (size_t)NN * FD + i * 4) = make_ushort4(0, 0, 0, 0);
    } else if (t < NN * FD / 4 + 48) {           // zero row NN of h1b
        int i = t - (NN * FD / 4 + 32);
        *(ushort4*)(h1b + (size_t)NN * HD + i * 4) = make_ushort4(0, 0, 0, 0);
    } else if (t < PREP_T) {                     // W0T[c][k] = W0[k][c]
        int u = t - (NN * FD / 4 + 48);
        int c = u >> 7, k = u & 127;
        w0t[u] = W0[k * HD + c];
    }
    if (t < NET * EE) {                          // degree count
        int et = t / EE;
        int e  = t - et * EE;
        const int* d = (et == 0) ? d0 : ((et == 1) ? d1 : d2);
        atomicAdd(&cnt[et * NN + d[e]], 1);
    }
}

// ---------------- 3-kernel parallel scan over x4-PADDED counts ----------------
__global__ void k_scan1(const int* __restrict__ cnt, int* __restrict__ bsum) {
    int et = blockIdx.x / 50, b = blockIdx.x % 50;
    const int* c = cnt + et * NN + b * 1000;
    __shared__ int sh[256];
    int t = threadIdx.x;
    int s = 0;
    for (int i = t; i < 1000; i += 256) s += (c[i] + 3) & ~3;
    sh[t] = s; __syncthreads();
    for (int off = 128; off > 0; off >>= 1) {
        if (t < off) sh[t] += sh[t + off];
        __syncthreads();
    }
    if (t == 0) bsum[blockIdx.x] = sh[0];
}
__global__ void k_scan2(const int* __restrict__ bsum, int* __restrict__ boff,
                        int* __restrict__ rowptr) {
    if (threadIdx.x == 0) {
        for (int et = 0; et < NET; ++et) {
            int run = 0;
            for (int b = 0; b < 50; ++b) {
                boff[et * 50 + b] = run;
                run += bsum[et * 50 + b];
            }
            rowptr[et * (NN + 1) + NN] = run;
        }
    }
}
__global__ void k_scan3(const int* __restrict__ cnt, const int* __restrict__ boff,
                        int* __restrict__ rowptr, int* __restrict__ cursor,
                        int* __restrict__ col, float* __restrict__ invd) {
    int blk = blockIdx.x;            // 0..149
    int et = blk / 50, b = blk % 50;
    const int* c = cnt + et * NN + b * 1000;
    __shared__ int sh[256];
    int t = threadIdx.x;
    int i0 = t * 4;
    int c4[4]; int s = 0;
    if (i0 < 1000) {
        #pragma unroll
        for (int q = 0; q < 4; ++q) { int v = c[i0 + q]; c4[q] = v; s += (v + 3) & ~3; }
    } else { c4[0] = c4[1] = c4[2] = c4[3] = 0; }
    sh[t] = s; __syncthreads();
    for (int off = 1; off < 256; off <<= 1) {
        int add = (t >= off) ? sh[t - off] : 0;
        __syncthreads();
        sh[t] += add;
        __syncthreads();
    }
    int run = boff[blk] + sh[t] - s;
    if (i0 < 1000) {
        int* rp = rowptr + et * (NN + 1);
        int* cu = cursor + et * NN;
        int* cl = col + et * CSTRIDE;
        float* iv = invd + et * NN;
        int node0 = b * 1000 + i0;
        #pragma unroll
        for (int q = 0; q < 4; ++q) {
            int node = node0 + q; int v = c4[q]; int pv = (v + 3) & ~3;
            rp[node] = run; cu[node] = run;
            iv[node] = 1.0f / (float)((v > 0) ? v : 1);
            for (int k = v; k < pv; ++k) cl[run + k] = NN;   // pad -> zero row
            run += pv;
        }
    }
}

__global__ void k_scatter(const int* __restrict__ s0, const int* __restrict__ d0,
                          const int* __restrict__ s1, const int* __restrict__ d1,
                          const int* __restrict__ s2, const int* __restrict__ d2,
                          int* __restrict__ cursor, int* __restrict__ col) {
    int t = blockIdx.x * 256 + threadIdx.x;
    if (t >= NET * EE) return;
    int et = t / EE;
    int e  = t - et * EE;
    const int* s = (et == 0) ? s0 : ((et == 1) ? s1 : s2);
    const int* d = (et == 0) ? d0 : ((et == 1) ? d1 : d2);
    int dd = d[e];
    int pos = atomicAdd(&cursor[et * NN + dd], 1);
    col[(size_t)et * CSTRIDE + pos] = s[e];
}

// ---------------- Layer 0 (+ fused sim head) ----------------
// One wave per node; slot s=lane>>4 gathers edge j+s (16 lanes x 16B = full row).
// After the slot-reduce, values are replicated x4 across slots -> slot s keeps
// ONLY its 2 dims (cndmask select) so tanh/mul/residual run 2-wide, not 8-wide.
// Epilogue reads transposed W0T (lane-contiguous float4) + distributed h stage.

__global__ __launch_bounds__(256) void k_layer0(
    const float* __restrict__ feat, const unsigned short* __restrict__ featb,
    const float* __restrict__ Wm, const float* __restrict__ bm,
    const float* __restrict__ w0t, const float* __restrict__ b0, const float* __restrict__ p0,
    const int* __restrict__ rowptr, const int* __restrict__ col,
    const float* __restrict__ invd,
    unsigned short* __restrict__ h1b, float* __restrict__ simout) {
    __shared__ float hbuf[4][FD];      // 2 KiB, one row per wave
    int w    = threadIdx.x >> 6;       // 4 nodes per block
    int lane = threadIdx.x & 63;
    int s    = lane >> 4;
    int i    = lane & 15;
    int d8   = i * 8;
    int node = (int)blockIdx.x * 4 + w;     // 50000 % 4 == 0

    const float4 fa = *(const float4*)(feat + (size_t)node * FD + d8);
    const float4 fb = *(const float4*)(feat + (size_t)node * FD + d8 + 4);

    float a0 = 0.f, a1 = 0.f;          // this slot's 2 dims only
    #pragma unroll
    for (int et = 0; et < NET; ++et) {
        const int* rp = rowptr + et * (NN + 1);
        int st = rp[node], t = rp[node + 1];
        const int* cc = col + (size_t)et * CSTRIDE;
        float x0 = 0.f, x1 = 0.f, x2 = 0.f, x3 = 0.f;
        float x4 = 0.f, x5 = 0.f, x6 = 0.f, x7 = 0.f;
        for (int base = st; base < t; base += 64) {
            int my = cc[base + lane];               // batched index load (OOB lanes unused)
            int m = t - base; if (m > 64) m = 64;   // multiple of 4
            int j = 0;
            for (; j + 8 <= m; j += 8) {
                int eA = __shfl(my, j + s, 64);
                int eB = __shfl(my, j + 4 + s, 64);
                uint4 uA = *(const uint4*)(featb + (size_t)eA * FD + d8);
                uint4 uB = *(const uint4*)(featb + (size_t)eB * FD + d8);
                x0 += bflo(uA.x); x1 += bfhiA(uA.x); x2 += bflo(uA.y); x3 += bfhiA(uA.y);
                x4 += bflo(uA.z); x5 += bfhiA(uA.z); x6 += bflo(uA.w); x7 += bfhiA(uA.w);
                x0 += bflo(uB.x); x1 += bfhiA(uB.x); x2 += bflo(uB.y); x3 += bfhiA(uB.y);
                x4 += bflo(uB.z); x5 += bfhiA(uB.z); x6 += bflo(uB.w); x7 += bfhiA(uB.w);
            }
            if (j < m) {                             // 4-edge tail (wave-uniform)
                int eA = __shfl(my, j + s, 64);
                uint4 uA = *(const uint4*)(featb + (size_t)eA * FD + d8);
                x0 += bflo(uA.x); x1 += bfhiA(uA.x); x2 += bflo(uA.y); x3 += bfhiA(uA.y);
                x4 += bflo(uA.z); x5 += bfhiA(uA.z); x6 += bflo(uA.w); x7 += bfhiA(uA.w);
            }
        }
        // reduce over the 4 edge-slots (lane bits 4,5)
        x0 += __shfl_xor(x0, 16, 64); x0 += __shfl_xor(x0, 32, 64);
        x1 += __shfl_xor(x1, 16, 64); x1 += __shfl_xor(x1, 32, 64);
        x2 += __shfl_xor(x2, 16, 64); x2 += __shfl_xor(x2, 32, 64);
        x3 += __shfl_xor(x3, 16, 64); x3 += __shfl_xor(x3, 32, 64);
        x4 += __shfl_xor(x4, 16, 64); x4 += __shfl_xor(x4, 32, 64);
        x5 += __shfl_xor(x5, 16, 64); x5 += __shfl_xor(x5, 32, 64);
        x6 += __shfl_xor(x6, 16, 64); x6 += __shfl_xor(x6, 32, 64);
        x7 += __shfl_xor(x7, 16, 64); x7 += __shfl_xor(x7, 32, 64);
        // slot s keeps dims (2s, 2s+1) of this lane's 8
        float v0 = (s & 2) ? ((s & 1) ? x6 : x4) : ((s & 1) ? x2 : x0);
        float v1 = (s & 2) ? ((s & 1) ? x7 : x5) : ((s & 1) ? x3 : x1);
        float inv = invd[et * NN + node];
        float pe = p0[et];
        a0 += pe * tanh_fast(v0 * inv);
        a1 += pe * tanh_fast(v1 * inv);
    }
    // residual dims for this slot
    float fr0 = (s & 2) ? ((s & 1) ? fb.z : fb.x) : ((s & 1) ? fa.z : fa.x);
    float fr1 = (s & 2) ? ((s & 1) ? fb.w : fb.y) : ((s & 1) ? fa.w : fa.y);
    float h0v = tanh_fast(a0 + fr0);
    float h1v = tanh_fast(a1 + fr1);

    // sim = tanh(feat @ Wm + bm); reduce over i (lane bits 0..3)
    float sp0 = fa.x * Wm[(d8 + 0) * 2 + 0] + fa.y * Wm[(d8 + 1) * 2 + 0]
              + fa.z * Wm[(d8 + 2) * 2 + 0] + fa.w * Wm[(d8 + 3) * 2 + 0]
              + fb.x * Wm[(d8 + 4) * 2 + 0] + fb.y * Wm[(d8 + 5) * 2 + 0]
              + fb.z * Wm[(d8 + 6) * 2 + 0] + fb.w * Wm[(d8 + 7) * 2 + 0];
    float sp1 = fa.x * Wm[(d8 + 0) * 2 + 1] + fa.y * Wm[(d8 + 1) * 2 + 1]
              + fa.z * Wm[(d8 + 2) * 2 + 1] + fa.w * Wm[(d8 + 3) * 2 + 1]
              + fb.x * Wm[(d8 + 4) * 2 + 1] + fb.y * Wm[(d8 + 5) * 2 + 1]
              + fb.z * Wm[(d8 + 6) * 2 + 1] + fb.w * Wm[(d8 + 7) * 2 + 1];
    #pragma unroll
    for (int off = 1; off <= 8; off <<= 1) {
        sp0 += __shfl_xor(sp0, off, 64);
        sp1 += __shfl_xor(sp1, off, 64);
    }
    if (lane == 0) {
        simout[node * 2 + 0] = tanh_fast(sp0 + bm[0]);
        simout[node * 2 + 1] = tanh_fast(sp1 + bm[1]);
    }

    // h @ W0 + b0: distributed h stage (each lane writes its 2 dims), W0T rows
    // lane-contiguous. Wave-synchronous LDS (same-wave write->read, DS in order).
    *(float2*)&hbuf[w][d8 + 2 * s] = make_float2(h0v, h1v);
    float o = b0[lane];
    const float* wrow = w0t + lane * FD;
    #pragma unroll 8
    for (int k4 = 0; k4 < FD; k4 += 4) {
        float4 hv = *(const float4*)&hbuf[w][k4];
        float4 wv = *(const float4*)(wrow + k4);
        o = fmaf(hv.x, wv.x, o);
        o = fmaf(hv.y, wv.y, o);
        o = fmaf(hv.z, wv.z, o);
        o = fmaf(hv.w, wv.w, o);
    }
    h1b[(size_t)node * HD + lane] = f2bf(o);
}

// ---------------- Layer 1 ----------------
// One wave per node; slot s keeps ONLY dim d4+s after the reduce; final output
// reduce runs over all 64 lanes (each lane owns one distinct hidden dim).

__global__ __launch_bounds__(256) void k_layer1(
    const unsigned short* __restrict__ h1b,
    const float* __restrict__ W1, const float* __restrict__ b1,
    const float* __restrict__ p1, const int* __restrict__ rowptr,
    const int* __restrict__ col, const float* __restrict__ invd,
    float* __restrict__ out) {
    int w    = threadIdx.x >> 6;
    int lane = threadIdx.x & 63;
    int s    = lane >> 4;
    int i    = lane & 15;
    int d4   = i * 4;
    int node = (int)blockIdx.x * 4 + w;

    uint2 hr = *(const uint2*)(h1b + (size_t)node * HD + d4);
    float r0 = bflo(hr.x), r1 = bfhiX(hr.x), r2 = bflo(hr.y), r3 = bfhiX(hr.y);

    float a = 0.f;                     // this slot's single dim
    #pragma unroll
    for (int et = 0; et < NET; ++et) {
        const int* rp = rowptr + et * (NN + 1);
        int st = rp[node], t = rp[node + 1];
        const int* cc = col + (size_t)et * CSTRIDE;
        float x0 = 0.f, x1 = 0.f, x2 = 0.f, x3 = 0.f;
        for (int base = st; base < t; base += 64) {
            int my = cc[base + lane];
            int m = t - base; if (m > 64) m = 64;   // multiple of 4
            int j = 0;
            for (; j + 8 <= m; j += 8) {
                int eA = __shfl(my, j + s, 64);
                int eB = __shfl(my, j + 4 + s, 64);
                uint2 uA = *(const uint2*)(h1b + (size_t)eA * HD + d4);
                uint2 uB = *(const uint2*)(h1b + (size_t)eB * HD + d4);
                x0 += bflo(uA.x); x1 += bfhiA(uA.x); x2 += bflo(uA.y); x3 += bfhiA(uA.y);
                x0 += bflo(uB.x); x1 += bfhiA(uB.x); x2 += bflo(uB.y); x3 += bfhiA(uB.y);
            }
            if (j < m) {
                int eA = __shfl(my, j + s, 64);
                uint2 uA = *(const uint2*)(h1b + (size_t)eA * HD + d4);
                x0 += bflo(uA.x); x1 += bfhiA(uA.x); x2 += bflo(uA.y); x3 += bfhiA(uA.y);
            }
        }
        x0 += __shfl_xor(x0, 16, 64); x0 += __shfl_xor(x0, 32, 64);
        x1 += __shfl_xor(x1, 16, 64); x1 += __shfl_xor(x1, 32, 64);
        x2 += __shfl_xor(x2, 16, 64); x2 += __shfl_xor(x2, 32, 64);
        x3 += __shfl_xor(x3, 16, 64); x3 += __shfl_xor(x3, 32, 64);
        float v = (s & 2) ? ((s & 1) ? x3 : x2) : ((s & 1) ? x1 : x0);
        float inv = invd[et * NN + node];
        a += p1[et] * tanh_fast(v * inv);
    }
    float r = (s & 2) ? ((s & 1) ? r3 : r2) : ((s & 1) ? r1 : r0);
    float g = tanh_fast(a + r);

    int dim = d4 + s;
    float q0 = g * W1[dim * 2 + 0];
    float q1 = g * W1[dim * 2 + 1];
    #pragma unroll
    for (int off = 1; off <= 32; off <<= 1) {
        q0 += __shfl_xor(q0, off, 64);
        q1 += __shfl_xor(q1, off, 64);
    }
    if (lane == 0) {
        out[node * 2 + 0] = q0 + b1[0];
        out[node * 2 + 1] = q1 + b1[1];
    }
}

// ---------------- launcher ----------------

extern "C" void kernel_launch(void* const* d_in, const int* in_sizes, int n_in,
                              void* d_out, int out_size, void* d_ws, size_t ws_size,
                              hipStream_t stream) {
    const float* feat = (const float*)d_in[0];
    const float* Wm   = (const float*)d_in[1];
    const float* bm   = (const float*)d_in[2];
    const float* W0   = (const float*)d_in[3];
    const float* b0   = (const float*)d_in[4];
    const float* W1   = (const float*)d_in[5];
    const float* b1   = (const float*)d_in[6];
    const float* p0   = (const float*)d_in[7];
    const float* p1   = (const float*)d_in[8];
    const int* src0 = (const int*)d_in[9];
    const int* dst0 = (const int*)d_in[10];
    const int* src1 = (const int*)d_in[11];
    const int* dst1 = (const int*)d_in[12];
    const int* src2 = (const int*)d_in[13];
    const int* dst2 = (const int*)d_in[14];

    char* ws = (char*)d_ws;
    int*            cnt    = (int*)(ws + 0);                   //   600,000 B
    int*            rowptr = (int*)(ws + 600000);              //   600,016 B
    int*            cursor = (int*)(ws + 1200016);             //   600,000 B
    float*          invd   = (float*)(ws + 1800016);           //   600,000 B
    int*            bsum   = (int*)(ws + 2400016);             //       608 B
    int*            boff   = (int*)(ws + 2400624);             //       608 B
    float*          w0t    = (float*)(ws + 2401232);           //    32,768 B
    int*            col    = (int*)(ws + 2434000);             // 7,800,256 B (+64 int pad)
    unsigned short* featb  = (unsigned short*)(ws + 10234256); // 12,800,256 B
    unsigned short* h1b    = (unsigned short*)(ws + 23034512); //  6,400,128 B
    // total ~29.4 MB

    float* out = (float*)d_out;           // [N,2] first
    float* sim = out + (size_t)NN * 2;    // [N,2] second

    hipMemsetAsync(cnt, 0, sizeof(int) * NET * NN, stream);
    k_prepcount<<<(PREP_T + 255) / 256, 256, 0, stream>>>(feat, featb, h1b, W0, w0t,
                                                          dst0, dst1, dst2, cnt);
    k_scan1<<<150, 256, 0, stream>>>(cnt, bsum);
    k_scan2<<<1, 64, 0, stream>>>(bsum, boff, rowptr);
    k_scan3<<<150, 256, 0, stream>>>(cnt, boff, rowptr, cursor, col, invd);
    k_scatter<<<(NET * EE + 255) / 256, 256, 0, stream>>>(src0, dst0, src1, dst1, src2, dst2,
                                                          cursor, col);
    k_layer0<<<NN / 4, 256, 0, stream>>>(feat, featb, Wm, bm, w0t, b0, p0,
                                         rowptr, col, invd, h1b, sim);
    k_layer1<<<NN / 4, 256, 0, stream>>>(h1b, W1, b1, p1, rowptr, col, invd, out);
}

// Round 12
// 334.731 us; speedup vs baseline: 1.3505x; 1.3505x over previous
//
#include <hip/hip_runtime.h>

#define NN 50000
#define EE 500000
#define FD 128
#define HD 64
#define NET 3
#define CSTRIDE 650000   // E + 3N (x4 padding: <=3 pads per node)

__device__ __forceinline__ unsigned short f2bf(float f) {
    union { float f; unsigned int i; } c; c.f = f;
    unsigned int u = c.i;
    return (unsigned short)((u + 0x7fffu + ((u >> 16) & 1u)) >> 16);   // RNE
}
__device__ __forceinline__ float tanh_fast(float x) {
    float e = __expf(2.0f * x);
    return 1.0f - __fdividef(2.0f, e + 1.0f);
}
// lo bf16 of a packed u32 -> f32 (exact)
__device__ __forceinline__ float bflo(unsigned int u) { return __uint_as_float(u << 16); }
// hi bf16 -> f32 APPROX (low mantissa garbage <= 2^-8 rel; below bf16 noise)
__device__ __forceinline__ float bfhiA(unsigned int u) { return __uint_as_float(u); }
// exact hi
__device__ __forceinline__ float bfhiX(unsigned int u) { return __uint_as_float(u & 0xffff0000u); }

// ---------------- prep + count (merged ranges) ----------------
#define PREP_T (NN * FD / 4 + 48)
__global__ void k_prepcount(const float* __restrict__ feat, unsigned short* __restrict__ featb,
                            unsigned short* __restrict__ h1b,
                            const int* __restrict__ d0, const int* __restrict__ d1,
                            const int* __restrict__ d2, int* __restrict__ cnt) {
    int t = blockIdx.x * 256 + threadIdx.x;
    if (t < NN * FD / 4) {                       // feat cvt, one float4 per thread
        float4 v = *(const float4*)(feat + (size_t)t * 4);
        ushort4 o;
        o.x = f2bf(v.x); o.y = f2bf(v.y); o.z = f2bf(v.z); o.w = f2bf(v.w);
        *(ushort4*)(featb + (size_t)t * 4) = o;
    } else if (t < NN * FD / 4 + 32) {           // zero row NN of featb
        int i = t - NN * FD / 4;
        *(ushort4*)(featb + (size_t)NN * FD + i * 4) = make_ushort4(0, 0, 0, 0);
    } else if (t < NN * FD / 4 + 48) {           // zero row NN of h1b
        int i = t - (NN * FD / 4 + 32);
        *(ushort4*)(h1b + (size_t)NN * HD + i * 4) = make_ushort4(0, 0, 0, 0);
    }
    if (t < NET * EE) {                          // degree count
        int et = t / EE;
        int e  = t - et * EE;
        const int* d = (et == 0) ? d0 : ((et == 1) ? d1 : d2);
        atomicAdd(&cnt[et * NN + d[e]], 1);
    }
}

// ---------------- 3-kernel parallel scan over x4-PADDED counts ----------------
__global__ void k_scan1(const int* __restrict__ cnt, int* __restrict__ bsum) {
    int et = blockIdx.x / 50, b = blockIdx.x % 50;
    const int* c = cnt + et * NN + b * 1000;
    __shared__ int sh[256];
    int t = threadIdx.x;
    int s = 0;
    for (int i = t; i < 1000; i += 256) s += (c[i] + 3) & ~3;
    sh[t] = s; __syncthreads();
    for (int off = 128; off > 0; off >>= 1) {
        if (t < off) sh[t] += sh[t + off];
        __syncthreads();
    }
    if (t == 0) bsum[blockIdx.x] = sh[0];
}
__global__ void k_scan2(const int* __restrict__ bsum, int* __restrict__ boff,
                        int* __restrict__ rowptr) {
    if (threadIdx.x == 0) {
        for (int et = 0; et < NET; ++et) {
            int run = 0;
            for (int b = 0; b < 50; ++b) {
                boff[et * 50 + b] = run;
                run += bsum[et * 50 + b];
            }
            rowptr[et * (NN + 1) + NN] = run;
        }
    }
}
__global__ void k_scan3(const int* __restrict__ cnt, const int* __restrict__ boff,
                        int* __restrict__ rowptr, int* __restrict__ cursor,
                        int* __restrict__ col, float* __restrict__ invd) {
    int blk = blockIdx.x;            // 0..149
    int et = blk / 50, b = blk % 50;
    const int* c = cnt + et * NN + b * 1000;
    __shared__ int sh[256];
    int t = threadIdx.x;
    int i0 = t * 4;
    int c4[4]; int s = 0;
    if (i0 < 1000) {
        #pragma unroll
        for (int q = 0; q < 4; ++q) { int v = c[i0 + q]; c4[q] = v; s += (v + 3) & ~3; }
    } else { c4[0] = c4[1] = c4[2] = c4[3] = 0; }
    sh[t] = s; __syncthreads();
    for (int off = 1; off < 256; off <<= 1) {
        int add = (t >= off) ? sh[t - off] : 0;
        __syncthreads();
        sh[t] += add;
        __syncthreads();
    }
    int run = boff[blk] + sh[t] - s;
    if (i0 < 1000) {
        int* rp = rowptr + et * (NN + 1);
        int* cu = cursor + et * NN;
        int* cl = col + et * CSTRIDE;
        float* iv = invd + et * NN;
        int node0 = b * 1000 + i0;
        #pragma unroll
        for (int q = 0; q < 4; ++q) {
            int node = node0 + q; int v = c4[q]; int pv = (v + 3) & ~3;
            rp[node] = run; cu[node] = run;
            iv[node] = 1.0f / (float)((v > 0) ? v : 1);
            for (int k = v; k < pv; ++k) cl[run + k] = NN;   // pad -> zero row
            run += pv;
        }
    }
}

__global__ void k_scatter(const int* __restrict__ s0, const int* __restrict__ d0,
                          const int* __restrict__ s1, const int* __restrict__ d1,
                          const int* __restrict__ s2, const int* __restrict__ d2,
                          int* __restrict__ cursor, int* __restrict__ col) {
    int t = blockIdx.x * 256 + threadIdx.x;
    if (t >= NET * EE) return;
    int et = t / EE;
    int e  = t - et * EE;
    const int* s = (et == 0) ? s0 : ((et == 1) ? s1 : s2);
    const int* d = (et == 0) ? d0 : ((et == 1) ? d1 : d2);
    int dd = d[e];
    int pos = atomicAdd(&cursor[et * NN + dd], 1);
    col[(size_t)et * CSTRIDE + pos] = s[e];
}

// ---------------- Layer 0 (+ fused sim head) ----------------
// One wave per node; slot s=lane>>4 gathers edge j+s (16 lanes x 16B = full row).
// After the slot-reduce, slot s keeps ONLY its 2 dims -> tanh/scale 2-wide.
// Distributed float2 h-stage. Epilogue: W0 GLOBAL, lane-coalesced scalar reads
// (R11 lesson: per-lane-contiguous W0T rows were fully uncoalesced, -75% perf).

__global__ __launch_bounds__(256) void k_layer0(
    const float* __restrict__ feat, const unsigned short* __restrict__ featb,
    const float* __restrict__ Wm, const float* __restrict__ bm,
    const float* __restrict__ W0, const float* __restrict__ b0, const float* __restrict__ p0,
    const int* __restrict__ rowptr, const int* __restrict__ col,
    const float* __restrict__ invd,
    unsigned short* __restrict__ h1b, float* __restrict__ simout) {
    __shared__ float hbuf[4][FD];      // 2 KiB, one row per wave
    int w    = threadIdx.x >> 6;       // 4 nodes per block
    int lane = threadIdx.x & 63;
    int s    = lane >> 4;
    int i    = lane & 15;
    int d8   = i * 8;
    int node = (int)blockIdx.x * 4 + w;     // 50000 % 4 == 0

    const float4 fa = *(const float4*)(feat + (size_t)node * FD + d8);
    const float4 fb = *(const float4*)(feat + (size_t)node * FD + d8 + 4);

    float a0 = 0.f, a1 = 0.f;          // this slot's 2 dims only
    #pragma unroll
    for (int et = 0; et < NET; ++et) {
        const int* rp = rowptr + et * (NN + 1);
        int st = rp[node], t = rp[node + 1];
        const int* cc = col + (size_t)et * CSTRIDE;
        float x0 = 0.f, x1 = 0.f, x2 = 0.f, x3 = 0.f;
        float x4 = 0.f, x5 = 0.f, x6 = 0.f, x7 = 0.f;
        for (int base = st; base < t; base += 64) {
            int my = cc[base + lane];               // batched index load (OOB lanes unused)
            int m = t - base; if (m > 64) m = 64;   // multiple of 4
            int j = 0;
            for (; j + 8 <= m; j += 8) {
                int eA = __shfl(my, j + s, 64);
                int eB = __shfl(my, j + 4 + s, 64);
                uint4 uA = *(const uint4*)(featb + (size_t)eA * FD + d8);
                uint4 uB = *(const uint4*)(featb + (size_t)eB * FD + d8);
                x0 += bflo(uA.x); x1 += bfhiA(uA.x); x2 += bflo(uA.y); x3 += bfhiA(uA.y);
                x4 += bflo(uA.z); x5 += bfhiA(uA.z); x6 += bflo(uA.w); x7 += bfhiA(uA.w);
                x0 += bflo(uB.x); x1 += bfhiA(uB.x); x2 += bflo(uB.y); x3 += bfhiA(uB.y);
                x4 += bflo(uB.z); x5 += bfhiA(uB.z); x6 += bflo(uB.w); x7 += bfhiA(uB.w);
            }
            if (j < m) {                             // 4-edge tail (wave-uniform)
                int eA = __shfl(my, j + s, 64);
                uint4 uA = *(const uint4*)(featb + (size_t)eA * FD + d8);
                x0 += bflo(uA.x); x1 += bfhiA(uA.x); x2 += bflo(uA.y); x3 += bfhiA(uA.y);
                x4 += bflo(uA.z); x5 += bfhiA(uA.z); x6 += bflo(uA.w); x7 += bfhiA(uA.w);
            }
        }
        // reduce over the 4 edge-slots (lane bits 4,5)
        x0 += __shfl_xor(x0, 16, 64); x0 += __shfl_xor(x0, 32, 64);
        x1 += __shfl_xor(x1, 16, 64); x1 += __shfl_xor(x1, 32, 64);
        x2 += __shfl_xor(x2, 16, 64); x2 += __shfl_xor(x2, 32, 64);
        x3 += __shfl_xor(x3, 16, 64); x3 += __shfl_xor(x3, 32, 64);
        x4 += __shfl_xor(x4, 16, 64); x4 += __shfl_xor(x4, 32, 64);
        x5 += __shfl_xor(x5, 16, 64); x5 += __shfl_xor(x5, 32, 64);
        x6 += __shfl_xor(x6, 16, 64); x6 += __shfl_xor(x6, 32, 64);
        x7 += __shfl_xor(x7, 16, 64); x7 += __shfl_xor(x7, 32, 64);
        // slot s keeps dims (2s, 2s+1) of this lane's 8
        float v0 = (s & 2) ? ((s & 1) ? x6 : x4) : ((s & 1) ? x2 : x0);
        float v1 = (s & 2) ? ((s & 1) ? x7 : x5) : ((s & 1) ? x3 : x1);
        float inv = invd[et * NN + node];
        float pe = p0[et];
        a0 += pe * tanh_fast(v0 * inv);
        a1 += pe * tanh_fast(v1 * inv);
    }
    // residual dims for this slot
    float fr0 = (s & 2) ? ((s & 1) ? fb.z : fb.x) : ((s & 1) ? fa.z : fa.x);
    float fr1 = (s & 2) ? ((s & 1) ? fb.w : fb.y) : ((s & 1) ? fa.w : fa.y);
    float h0v = tanh_fast(a0 + fr0);
    float h1v = tanh_fast(a1 + fr1);

    // sim = tanh(feat @ Wm + bm); reduce over i (lane bits 0..3)
    float sp0 = fa.x * Wm[(d8 + 0) * 2 + 0] + fa.y * Wm[(d8 + 1) * 2 + 0]
              + fa.z * Wm[(d8 + 2) * 2 + 0] + fa.w * Wm[(d8 + 3) * 2 + 0]
              + fb.x * Wm[(d8 + 4) * 2 + 0] + fb.y * Wm[(d8 + 5) * 2 + 0]
              + fb.z * Wm[(d8 + 6) * 2 + 0] + fb.w * Wm[(d8 + 7) * 2 + 0];
    float sp1 = fa.x * Wm[(d8 + 0) * 2 + 1] + fa.y * Wm[(d8 + 1) * 2 + 1]
              + fa.z * Wm[(d8 + 2) * 2 + 1] + fa.w * Wm[(d8 + 3) * 2 + 1]
              + fb.x * Wm[(d8 + 4) * 2 + 1] + fb.y * Wm[(d8 + 5) * 2 + 1]
              + fb.z * Wm[(d8 + 6) * 2 + 1] + fb.w * Wm[(d8 + 7) * 2 + 1];
    #pragma unroll
    for (int off = 1; off <= 8; off <<= 1) {
        sp0 += __shfl_xor(sp0, off, 64);
        sp1 += __shfl_xor(sp1, off, 64);
    }
    if (lane == 0) {
        simout[node * 2 + 0] = tanh_fast(sp0 + bm[0]);
        simout[node * 2 + 1] = tanh_fast(sp1 + bm[1]);
    }

    // h @ W0 + b0: distributed h stage (each lane writes its 2 dims), W0 from
    // global, lane-coalesced. Wave-synchronous LDS (same-wave write->read).
    *(float2*)&hbuf[w][d8 + 2 * s] = make_float2(h0v, h1v);
    float o = b0[lane];
    #pragma unroll 8
    for (int k4 = 0; k4 < FD; k4 += 4) {
        float4 hv = *(const float4*)&hbuf[w][k4];
        o = fmaf(hv.x, W0[(k4 + 0) * HD + lane], o);
        o = fmaf(hv.y, W0[(k4 + 1) * HD + lane], o);
        o = fmaf(hv.z, W0[(k4 + 2) * HD + lane], o);
        o = fmaf(hv.w, W0[(k4 + 3) * HD + lane], o);
    }
    h1b[(size_t)node * HD + lane] = f2bf(o);
}

// ---------------- Layer 1 ----------------
// One wave per node; slot s keeps ONLY dim d4+s after the reduce; final output
// reduce runs over all 64 lanes (each lane owns one distinct hidden dim).

__global__ __launch_bounds__(256) void k_layer1(
    const unsigned short* __restrict__ h1b,
    const float* __restrict__ W1, const float* __restrict__ b1,
    const float* __restrict__ p1, const int* __restrict__ rowptr,
    const int* __restrict__ col, const float* __restrict__ invd,
    float* __restrict__ out) {
    int w    = threadIdx.x >> 6;
    int lane = threadIdx.x & 63;
    int s    = lane >> 4;
    int i    = lane & 15;
    int d4   = i * 4;
    int node = (int)blockIdx.x * 4 + w;

    uint2 hr = *(const uint2*)(h1b + (size_t)node * HD + d4);
    float r0 = bflo(hr.x), r1 = bfhiX(hr.x), r2 = bflo(hr.y), r3 = bfhiX(hr.y);

    float a = 0.f;                     // this slot's single dim
    #pragma unroll
    for (int et = 0; et < NET; ++et) {
        const int* rp = rowptr + et * (NN + 1);
        int st = rp[node], t = rp[node + 1];
        const int* cc = col + (size_t)et * CSTRIDE;
        float x0 = 0.f, x1 = 0.f, x2 = 0.f, x3 = 0.f;
        for (int base = st; base < t; base += 64) {
            int my = cc[base + lane];
            int m = t - base; if (m > 64) m = 64;   // multiple of 4
            int j = 0;
            for (; j + 8 <= m; j += 8) {
                int eA = __shfl(my, j + s, 64);
                int eB = __shfl(my, j + 4 + s, 64);
                uint2 uA = *(const uint2*)(h1b + (size_t)eA * HD + d4);
                uint2 uB = *(const uint2*)(h1b + (size_t)eB * HD + d4);
                x0 += bflo(uA.x); x1 += bfhiA(uA.x); x2 += bflo(uA.y); x3 += bfhiA(uA.y);
                x0 += bflo(uB.x); x1 += bfhiA(uB.x); x2 += bflo(uB.y); x3 += bfhiA(uB.y);
            }
            if (j < m) {
                int eA = __shfl(my, j + s, 64);
                uint2 uA = *(const uint2*)(h1b + (size_t)eA * HD + d4);
                x0 += bflo(uA.x); x1 += bfhiA(uA.x); x2 += bflo(uA.y); x3 += bfhiA(uA.y);
            }
        }
        x0 += __shfl_xor(x0, 16, 64); x0 += __shfl_xor(x0, 32, 64);
        x1 += __shfl_xor(x1, 16, 64); x1 += __shfl_xor(x1, 32, 64);
        x2 += __shfl_xor(x2, 16, 64); x2 += __shfl_xor(x2, 32, 64);
        x3 += __shfl_xor(x3, 16, 64); x3 += __shfl_xor(x3, 32, 64);
        float v = (s & 2) ? ((s & 1) ? x3 : x2) : ((s & 1) ? x1 : x0);
        float inv = invd[et * NN + node];
        a += p1[et] * tanh_fast(v * inv);
    }
    float r = (s & 2) ? ((s & 1) ? r3 : r2) : ((s & 1) ? r1 : r0);
    float g = tanh_fast(a + r);

    int dim = d4 + s;
    float q0 = g * W1[dim * 2 + 0];
    float q1 = g * W1[dim * 2 + 1];
    #pragma unroll
    for (int off = 1; off <= 32; off <<= 1) {
        q0 += __shfl_xor(q0, off, 64);
        q1 += __shfl_xor(q1, off, 64);
    }
    if (lane == 0) {
        out[node * 2 + 0] = q0 + b1[0];
        out[node * 2 + 1] = q1 + b1[1];
    }
}

// ---------------- launcher ----------------

extern "C" void kernel_launch(void* const* d_in, const int* in_sizes, int n_in,
                              void* d_out, int out_size, void* d_ws, size_t ws_size,
                              hipStream_t stream) {
    const float* feat = (const float*)d_in[0];
    const float* Wm   = (const float*)d_in[1];
    const float* bm   = (const float*)d_in[2];
    const float* W0   = (const float*)d_in[3];
    const float* b0   = (const float*)d_in[4];
    const float* W1   = (const float*)d_in[5];
    const float* b1   = (const float*)d_in[6];
    const float* p0   = (const float*)d_in[7];
    const float* p1   = (const float*)d_in[8];
    const int* src0 = (const int*)d_in[9];
    const int* dst0 = (const int*)d_in[10];
    const int* src1 = (const int*)d_in[11];
    const int* dst1 = (const int*)d_in[12];
    const int* src2 = (const int*)d_in[13];
    const int* dst2 = (const int*)d_in[14];

    char* ws = (char*)d_ws;
    int*            cnt    = (int*)(ws + 0);                   //   600,000 B
    int*            rowptr = (int*)(ws + 600000);              //   600,016 B
    int*            cursor = (int*)(ws + 1200016);             //   600,000 B
    float*          invd   = (float*)(ws + 1800016);           //   600,000 B
    int*            bsum   = (int*)(ws + 2400016);             //       608 B
    int*            boff   = (int*)(ws + 2400624);             //       608 B
    int*            col    = (int*)(ws + 2401232);             // 7,800,256 B (+64 int pad)
    unsigned short* featb  = (unsigned short*)(ws + 10201488); // 12,800,256 B
    unsigned short* h1b    = (unsigned short*)(ws + 23001744); //  6,400,128 B
    // total ~29.4 MB

    float* out = (float*)d_out;           // [N,2] first
    float* sim = out + (size_t)NN * 2;    // [N,2] second

    hipMemsetAsync(cnt, 0, sizeof(int) * NET * NN, stream);
    k_prepcount<<<(PREP_T + 255) / 256, 256, 0, stream>>>(feat, featb, h1b,
                                                          dst0, dst1, dst2, cnt);
    k_scan1<<<150, 256, 0, stream>>>(cnt, bsum);
    k_scan2<<<1, 64, 0, stream>>>(bsum, boff, rowptr);
    k_scan3<<<150, 256, 0, stream>>>(cnt, boff, rowptr, cursor, col, invd);
    k_scatter<<<(NET * EE + 255) / 256, 256, 0, stream>>>(src0, dst0, src1, dst1, src2, dst2,
                                                          cursor, col);
    k_layer0<<<NN / 4, 256, 0, stream>>>(feat, featb, Wm, bm, W0, b0, p0,
                                         rowptr, col, invd, h1b, sim);
    k_layer1<<<NN / 4, 256, 0, stream>>>(h1b, W1, b1, p1, rowptr, col, invd, out);
}